// Round 1
// baseline (1205.832 us; speedup 1.0000x reference)
//
#include <hip/hip_runtime.h>
#include <math.h>

#define DIM 64

// ---------------- CSR build ----------------

__global__ void count_kernel(const int* __restrict__ dst, int* __restrict__ counts, int E) {
    int e = blockIdx.x * blockDim.x + threadIdx.x;
    if (e < E) atomicAdd(&counts[dst[e]], 1);
}

// 256 threads, 4 elems/thread => 1024 elems/block
__global__ void scan1_kernel(const int* __restrict__ counts, int* __restrict__ excl,
                             int* __restrict__ blk_sums, int n) {
    __shared__ int sdata[256];
    int t = threadIdx.x;
    int base = blockIdx.x * 1024 + t * 4;
    int v0 = (base + 0 < n) ? counts[base + 0] : 0;
    int v1 = (base + 1 < n) ? counts[base + 1] : 0;
    int v2 = (base + 2 < n) ? counts[base + 2] : 0;
    int v3 = (base + 3 < n) ? counts[base + 3] : 0;
    int tsum = v0 + v1 + v2 + v3;
    sdata[t] = tsum;
    __syncthreads();
    for (int off = 1; off < 256; off <<= 1) {
        int x = (t >= off) ? sdata[t - off] : 0;
        __syncthreads();
        sdata[t] += x;
        __syncthreads();
    }
    int run = sdata[t] - tsum;  // exclusive prefix for this thread
    if (base + 0 < n) excl[base + 0] = run; run += v0;
    if (base + 1 < n) excl[base + 1] = run; run += v1;
    if (base + 2 < n) excl[base + 2] = run; run += v2;
    if (base + 3 < n) excl[base + 3] = run;
    if (t == 255) blk_sums[blockIdx.x] = sdata[255];
}

// single block, nb <= 128
__global__ void scan2_kernel(int* __restrict__ blk_sums, int nb) {
    __shared__ int s[128];
    int t = threadIdx.x;
    s[t] = (t < nb) ? blk_sums[t] : 0;
    __syncthreads();
    for (int off = 1; off < 128; off <<= 1) {
        int x = (t >= off) ? s[t - off] : 0;
        __syncthreads();
        s[t] += x;
        __syncthreads();
    }
    if (t < nb) blk_sums[t] = (t > 0) ? s[t - 1] : 0;
}

__global__ void scan3_kernel(int* __restrict__ excl, const int* __restrict__ blk_sums,
                             int n, int total) {
    int i = blockIdx.x * blockDim.x + threadIdx.x;
    if (i < n) excl[i] += blk_sums[i >> 10];
    if (i == 0) excl[n] = total;
}

__global__ void scatter_kernel(const int* __restrict__ src, const int* __restrict__ dst,
                               const int* __restrict__ row_ptr, int* __restrict__ fill,
                               int* __restrict__ src_sorted, int* __restrict__ node_sorted, int E) {
    int e = blockIdx.x * blockDim.x + threadIdx.x;
    if (e < E) {
        int d = dst[e];
        int pos = row_ptr[d] + atomicAdd(&fill[d], 1);
        src_sorted[pos] = src[e];
        node_sorted[pos] = d;
    }
}

// ---------------- per-layer kernels ----------------

// feat = h @ W ; el = feat.al ; er = feat.ar   (one wave per row)
__global__ __launch_bounds__(256) void gemm64_kernel(
    const float* __restrict__ h, const float* __restrict__ W,
    const float* __restrict__ al, const float* __restrict__ ar,
    float* __restrict__ feat, float* __restrict__ el, float* __restrict__ er, int n) {
    __shared__ float Ws[DIM * DIM];
    __shared__ float avec[2 * DIM];
    int t = threadIdx.x;
    for (int i = t; i < DIM * DIM; i += 256) Ws[i] = W[i];
    if (t < 2 * DIM) avec[t] = (t < DIM) ? al[t] : ar[t - DIM];
    __syncthreads();
    int lane = t & 63;
    int w = t >> 6;
    float a_l = avec[lane], a_r = avec[DIM + lane];
    int stride = gridDim.x * 4;
    for (int row = blockIdx.x * 4 + w; row < n; row += stride) {
        float hv = h[(size_t)row * DIM + lane];
        float acc = 0.f;
#pragma unroll
        for (int k = 0; k < DIM; k++) {
            acc = fmaf(__shfl(hv, k, 64), Ws[k * DIM + lane], acc);
        }
        feat[(size_t)row * DIM + lane] = acc;
        float pl = acc * a_l, pr = acc * a_r;
#pragma unroll
        for (int off = 32; off; off >>= 1) {
            pl += __shfl_down(pl, off, 64);
            pr += __shfl_down(pr, off, 64);
        }
        if (lane == 0) { el[row] = pl; er[row] = pr; }
    }
}

// e_sorted[pos] = leaky_relu(el[src] + er[dst]) in CSR order (coalesced)
__global__ void edge_kernel(const int* __restrict__ src_sorted, const int* __restrict__ node_sorted,
                            const float* __restrict__ el, const float* __restrict__ er,
                            float* __restrict__ e_sorted, int E) {
    int i = blockIdx.x * blockDim.x + threadIdx.x;
    if (i < E) {
        float v = el[src_sorted[i]] + er[node_sorted[i]];
        e_sorted[i] = (v > 0.f) ? v : 0.2f * v;
    }
}

// one wave per dst node: online softmax over its edge range, then weighted gather
__global__ __launch_bounds__(256) void aggregate_kernel(
    const int* __restrict__ row_ptr, const int* __restrict__ src_sorted,
    const float* __restrict__ e_sorted, const float* __restrict__ feat,
    const float* __restrict__ bias, float* __restrict__ out, int n) {
    int t = threadIdx.x, lane = t & 63;
    int node = blockIdx.x * 4 + (t >> 6);
    if (node >= n) return;
    int start = row_ptr[node], end = row_ptr[node + 1];

    // per-lane online softmax state
    float m = -INFINITY, s = 0.f;
    for (int i = start + lane; i < end; i += 64) {
        float e = e_sorted[i];
        float mn = fmaxf(m, e);
        s = s * __expf(m - mn) + __expf(e - mn);
        m = mn;
    }
    // wave combine (lane 0's cone stays in-bounds)
#pragma unroll
    for (int off = 32; off; off >>= 1) {
        float mo = __shfl_down(m, off, 64);
        float so = __shfl_down(s, off, 64);
        float mn = fmaxf(m, mo);
        float sa = (m == -INFINITY) ? 0.f : s * __expf(m - mn);
        float sb = (mo == -INFINITY) ? 0.f : so * __expf(mo - mn);
        s = sa + sb;
        m = mn;
    }
    m = __shfl(m, 0, 64);
    s = __shfl(s, 0, 64);
    float inv_s = (s > 0.f) ? 1.f / s : 0.f;

    float acc = 0.f;
    for (int i = start; i < end; i++) {
        int sn = src_sorted[i];                      // broadcast load
        float wgt = __expf(e_sorted[i] - m) * inv_s; // broadcast load
        acc = fmaf(wgt, feat[(size_t)sn * DIM + lane], acc);
    }
    out[(size_t)node * DIM + lane] = acc + bias[lane];
}

// column sums / sumsq
__global__ __launch_bounds__(256) void bn_stats_kernel(const float* __restrict__ h,
                                                       float* __restrict__ stats, int n) {
    __shared__ float ls[256], lss[256];
    int t = threadIdx.x, lane = t & 63;
    int w = blockIdx.x * 4 + (t >> 6);
    int stride = gridDim.x * 4;
    float s = 0.f, ss = 0.f;
    for (int row = w; row < n; row += stride) {
        float v = h[(size_t)row * DIM + lane];
        s += v;
        ss = fmaf(v, v, ss);
    }
    ls[t] = s; lss[t] = ss;
    __syncthreads();
    if (t < 64) {
        float a = ls[t] + ls[t + 64] + ls[t + 128] + ls[t + 192];
        float b = lss[t] + lss[t + 64] + lss[t + 128] + lss[t + 192];
        atomicAdd(&stats[t], a);
        atomicAdd(&stats[64 + t], b);
    }
}

__global__ void bn_apply_kernel(float* __restrict__ h, const float* __restrict__ stats,
                                const float* __restrict__ g, const float* __restrict__ beta,
                                int n, int do_elu) {
    int i = blockIdx.x * blockDim.x + threadIdx.x;
    int total = n * DIM;
    int stride = gridDim.x * blockDim.x;
    float invN = 1.f / (float)n;
    for (; i < total; i += stride) {
        int c = i & 63;
        float mu = stats[c] * invN;
        float var = fmaf(-mu, mu, stats[DIM + c] * invN);
        float x = (h[i] - mu) * rsqrtf(var + 1e-5f) * g[c] + beta[c];
        if (do_elu && x < 0.f) x = expm1f(x);
        h[i] = x;
    }
}

// ---------------- launch ----------------

extern "C" void kernel_launch(void* const* d_in, const int* in_sizes, int n_in,
                              void* d_out, int out_size, void* d_ws, size_t ws_size,
                              hipStream_t stream) {
    const float* nw = (const float*)d_in[0];
    const int* src = (const int*)d_in[2];
    const int* dst = (const int*)d_in[3];
    const int N = in_sizes[0] / DIM;
    const int E = in_sizes[2];

    char* ws = (char*)d_ws;
    size_t off = 0;
    auto alloc = [&](size_t bytes) -> void* {
        void* p = ws + off;
        off += (bytes + 255) & ~(size_t)255;
        return p;
    };
    int* counts      = (int*)alloc((size_t)N * 4);
    int* row_ptr     = (int*)alloc(((size_t)N + 1) * 4);
    int* blk_sums    = (int*)alloc(512);
    int* src_sorted  = (int*)alloc((size_t)E * 4);
    int* node_sorted = (int*)alloc((size_t)E * 4);
    float* e_sorted  = (float*)alloc((size_t)E * 4);
    float* el        = (float*)alloc((size_t)N * 4);
    float* er        = (float*)alloc((size_t)N * 4);
    float* feat      = (float*)alloc((size_t)N * DIM * 4);
    float* hbuf      = (float*)alloc((size_t)N * DIM * 4);
    float* stats     = (float*)alloc(512);

    int egrid = (E + 255) / 256;
    int nb = (N + 1023) / 1024;  // 98 <= 128

    // CSR build (once; same graph for all 3 layers)
    hipMemsetAsync(counts, 0, (size_t)N * 4, stream);
    count_kernel<<<egrid, 256, 0, stream>>>(dst, counts, E);
    scan1_kernel<<<nb, 256, 0, stream>>>(counts, row_ptr, blk_sums, N);
    scan2_kernel<<<1, 128, 0, stream>>>(blk_sums, nb);
    scan3_kernel<<<(N + 255) / 256, 256, 0, stream>>>(row_ptr, blk_sums, N, E);
    hipMemsetAsync(counts, 0, (size_t)N * 4, stream);  // reuse as fill
    scatter_kernel<<<egrid, 256, 0, stream>>>(src, dst, row_ptr, counts,
                                              src_sorted, node_sorted, E);

    for (int l = 0; l < 3; l++) {
        const float* W    = (const float*)d_in[4 + 6 * l];
        const float* al   = (const float*)d_in[5 + 6 * l];
        const float* ar   = (const float*)d_in[6 + 6 * l];
        const float* b    = (const float*)d_in[7 + 6 * l];
        const float* g    = (const float*)d_in[8 + 6 * l];
        const float* beta = (const float*)d_in[9 + 6 * l];
        const float* hin = (l == 0) ? nw : hbuf;
        float* hout = (l == 2) ? (float*)d_out : hbuf;

        gemm64_kernel<<<1024, 256, 0, stream>>>(hin, W, al, ar, feat, el, er, N);
        edge_kernel<<<egrid, 256, 0, stream>>>(src_sorted, node_sorted, el, er, e_sorted, E);
        aggregate_kernel<<<(N + 3) / 4, 256, 0, stream>>>(row_ptr, src_sorted, e_sorted,
                                                          feat, b, hout, N);
        hipMemsetAsync(stats, 0, 512, stream);
        bn_stats_kernel<<<256, 256, 0, stream>>>(hout, stats, N);
        bn_apply_kernel<<<2048, 256, 0, stream>>>(hout, stats, g, beta, N, (l < 2) ? 1 : 0);
    }
}

// Round 2
// 890.125 us; speedup vs baseline: 1.3547x; 1.3547x over previous
//
#include <hip/hip_runtime.h>
#include <math.h>

#define DIM 64

// ---------------- CSR build ----------------

__global__ void count_kernel(const int* __restrict__ dst, int* __restrict__ counts, int E) {
    int e = blockIdx.x * blockDim.x + threadIdx.x;
    if (e < E) atomicAdd(&counts[dst[e]], 1);
}

// 256 threads, 4 elems/thread => 1024 elems/block
__global__ void scan1_kernel(const int* __restrict__ counts, int* __restrict__ excl,
                             int* __restrict__ blk_sums, int n) {
    __shared__ int sdata[256];
    int t = threadIdx.x;
    int base = blockIdx.x * 1024 + t * 4;
    int v0 = (base + 0 < n) ? counts[base + 0] : 0;
    int v1 = (base + 1 < n) ? counts[base + 1] : 0;
    int v2 = (base + 2 < n) ? counts[base + 2] : 0;
    int v3 = (base + 3 < n) ? counts[base + 3] : 0;
    int tsum = v0 + v1 + v2 + v3;
    sdata[t] = tsum;
    __syncthreads();
    for (int off = 1; off < 256; off <<= 1) {
        int x = (t >= off) ? sdata[t - off] : 0;
        __syncthreads();
        sdata[t] += x;
        __syncthreads();
    }
    int run = sdata[t] - tsum;  // exclusive prefix for this thread
    if (base + 0 < n) excl[base + 0] = run; run += v0;
    if (base + 1 < n) excl[base + 1] = run; run += v1;
    if (base + 2 < n) excl[base + 2] = run; run += v2;
    if (base + 3 < n) excl[base + 3] = run;
    if (t == 255) blk_sums[blockIdx.x] = sdata[255];
}

// single block, nb <= 128
__global__ void scan2_kernel(int* __restrict__ blk_sums, int nb) {
    __shared__ int s[128];
    int t = threadIdx.x;
    s[t] = (t < nb) ? blk_sums[t] : 0;
    __syncthreads();
    for (int off = 1; off < 128; off <<= 1) {
        int x = (t >= off) ? s[t - off] : 0;
        __syncthreads();
        s[t] += x;
        __syncthreads();
    }
    if (t < nb) blk_sums[t] = (t > 0) ? s[t - 1] : 0;
}

__global__ void scan3_kernel(int* __restrict__ excl, const int* __restrict__ blk_sums,
                             int n, int total) {
    int i = blockIdx.x * blockDim.x + threadIdx.x;
    if (i < n) excl[i] += blk_sums[i >> 10];
    if (i == 0) excl[n] = total;
}

__global__ void scatter_kernel(const int* __restrict__ src, const int* __restrict__ dst,
                               const int* __restrict__ row_ptr, int* __restrict__ fill,
                               int* __restrict__ src_sorted, int E) {
    int e = blockIdx.x * blockDim.x + threadIdx.x;
    if (e < E) {
        int d = dst[e];
        int pos = row_ptr[d] + atomicAdd(&fill[d], 1);
        src_sorted[pos] = src[e];
    }
}

// ---------------- per-layer kernels ----------------

// feat = bnelu(h) @ W ; el = feat.al ; er = feat.ar   (one wave per row)
// BN+ELU of the PREVIOUS layer is fused into the input load (do_bn).
__global__ __launch_bounds__(256) void gemm64_kernel(
    const float* __restrict__ h, const float* __restrict__ W,
    const float* __restrict__ al, const float* __restrict__ ar,
    const float* __restrict__ stats, const float* __restrict__ g,
    const float* __restrict__ beta, int do_bn, float invN,
    float* __restrict__ feat, float* __restrict__ el, float* __restrict__ er, int n) {
    __shared__ float Ws[DIM * DIM];
    __shared__ float avec[2 * DIM];
    int t = threadIdx.x;
    for (int i = t; i < DIM * DIM; i += 256) Ws[i] = W[i];
    if (t < 2 * DIM) avec[t] = (t < DIM) ? al[t] : ar[t - DIM];
    __syncthreads();
    int lane = t & 63;
    int w = t >> 6;
    float a_l = avec[lane], a_r = avec[DIM + lane];
    float scale = 1.f, shift = 0.f;
    if (do_bn) {
        float mu = stats[lane] * invN;
        float var = fmaf(-mu, mu, stats[DIM + lane] * invN);
        float inv = rsqrtf(var + 1e-5f) * g[lane];
        scale = inv;
        shift = beta[lane] - mu * inv;
    }
    int stride = gridDim.x * 4;
    for (int row = blockIdx.x * 4 + w; row < n; row += stride) {
        float hv = h[(size_t)row * DIM + lane];
        if (do_bn) {
            hv = fmaf(hv, scale, shift);
            if (hv < 0.f) hv = expm1f(hv);   // ELU
        }
        float acc = 0.f;
#pragma unroll
        for (int k = 0; k < DIM; k++) {
            acc = fmaf(__shfl(hv, k, 64), Ws[k * DIM + lane], acc);
        }
        feat[(size_t)row * DIM + lane] = acc;
        float pl = acc * a_l, pr = acc * a_r;
#pragma unroll
        for (int off = 32; off; off >>= 1) {
            pl += __shfl_down(pl, off, 64);
            pr += __shfl_down(pr, off, 64);
        }
        if (lane == 0) { el[row] = pl; er[row] = pr; }
    }
}

// Fused: edge score (leaky-relu) + per-dst softmax (max & sum) + alpha.
// One quarter-wave (16 lanes) per dst node. alpha overwrites e in-place.
__global__ __launch_bounds__(256) void attn_kernel(
    const int* __restrict__ row_ptr, const int* __restrict__ src_sorted,
    const float* __restrict__ el, const float* __restrict__ er,
    float* __restrict__ ebuf, int n) {
    int t = threadIdx.x;
    int li = t & 15;
    int node = blockIdx.x * 16 + (t >> 4);
    if (node >= n) return;
    int start = row_ptr[node], end = row_ptr[node + 1];
    float er_n = er[node];

    float m = -INFINITY, s = 0.f;
    for (int i = start + li; i < end; i += 16) {
        float v = el[src_sorted[i]] + er_n;
        v = (v > 0.f) ? v : 0.2f * v;
        ebuf[i] = v;
        float mn = fmaxf(m, v);
        s = s * __expf(m - mn) + __expf(v - mn);
        m = mn;
    }
    // reduce across the 16 lanes of this quarter-wave
#pragma unroll
    for (int off = 8; off; off >>= 1) {
        float mo = __shfl_xor(m, off, 64);
        float so = __shfl_xor(s, off, 64);
        float mn = fmaxf(m, mo);
        float sa = (m == -INFINITY) ? 0.f : s * __expf(m - mn);
        float sb = (mo == -INFINITY) ? 0.f : so * __expf(mo - mn);
        s = sa + sb;
        m = mn;
    }
    float inv_s = (s > 0.f) ? 1.f / s : 0.f;
    for (int i = start + li; i < end; i += 16) {
        ebuf[i] = __expf(ebuf[i] - m) * inv_s;   // alpha, in place
    }
}

// one wave per dst node; 4 quarter-waves process 4 edges concurrently,
// each lane holds a float4 slice of the 64-dim row.
__global__ __launch_bounds__(256) void aggregate_kernel(
    const int* __restrict__ row_ptr, const int* __restrict__ src_sorted,
    const float* __restrict__ alpha, const float* __restrict__ feat,
    const float* __restrict__ bias, float* __restrict__ out, int n) {
    int t = threadIdx.x, lane = t & 63;
    int q = lane >> 4;        // edge slot 0..3
    int li = lane & 15;       // dim quad 0..15
    int node = blockIdx.x * 4 + (t >> 6);
    if (node >= n) return;
    int start = row_ptr[node], end = row_ptr[node + 1];
    const float4* featv = (const float4*)feat;

    float4 acc = {0.f, 0.f, 0.f, 0.f};
    int i = start;
    for (; i + 4 <= end; i += 4) {          // 4 edges, all valid
        int idx = i + q;
        float a = alpha[idx];
        int sn = src_sorted[idx];
        float4 f = featv[(size_t)sn * 16 + li];
        acc.x = fmaf(a, f.x, acc.x);
        acc.y = fmaf(a, f.y, acc.y);
        acc.z = fmaf(a, f.z, acc.z);
        acc.w = fmaf(a, f.w, acc.w);
    }
    if (i < end) {                          // masked tail
        int idx = i + q;
        bool valid = idx < end;
        int idc = valid ? idx : end - 1;
        float a = valid ? alpha[idc] : 0.f;
        int sn = src_sorted[idc];
        float4 f = featv[(size_t)sn * 16 + li];
        acc.x = fmaf(a, f.x, acc.x);
        acc.y = fmaf(a, f.y, acc.y);
        acc.z = fmaf(a, f.z, acc.z);
        acc.w = fmaf(a, f.w, acc.w);
    }
    // combine the 4 edge slots (butterfly over lane bits 4,5)
#pragma unroll
    for (int off = 16; off <= 32; off <<= 1) {
        acc.x += __shfl_xor(acc.x, off, 64);
        acc.y += __shfl_xor(acc.y, off, 64);
        acc.z += __shfl_xor(acc.z, off, 64);
        acc.w += __shfl_xor(acc.w, off, 64);
    }
    if (q == 0) {
        float4 b4 = ((const float4*)bias)[li];
        acc.x += b4.x; acc.y += b4.y; acc.z += b4.z; acc.w += b4.w;
        ((float4*)out)[(size_t)node * 16 + li] = acc;
    }
}

// column sums / sumsq
__global__ __launch_bounds__(256) void bn_stats_kernel(const float* __restrict__ h,
                                                       float* __restrict__ stats, int n) {
    __shared__ float ls[256], lss[256];
    int t = threadIdx.x, lane = t & 63;
    int w = blockIdx.x * 4 + (t >> 6);
    int stride = gridDim.x * 4;
    float s = 0.f, ss = 0.f;
    for (int row = w; row < n; row += stride) {
        float v = h[(size_t)row * DIM + lane];
        s += v;
        ss = fmaf(v, v, ss);
    }
    ls[t] = s; lss[t] = ss;
    __syncthreads();
    if (t < 64) {
        float a = ls[t] + ls[t + 64] + ls[t + 128] + ls[t + 192];
        float b = lss[t] + lss[t + 64] + lss[t + 128] + lss[t + 192];
        atomicAdd(&stats[t], a);
        atomicAdd(&stats[64 + t], b);
    }
}

__global__ void bn_apply_kernel(float* __restrict__ h, const float* __restrict__ stats,
                                const float* __restrict__ g, const float* __restrict__ beta,
                                int n, int do_elu) {
    int i = blockIdx.x * blockDim.x + threadIdx.x;
    int total = n * DIM;
    int stride = gridDim.x * blockDim.x;
    float invN = 1.f / (float)n;
    for (; i < total; i += stride) {
        int c = i & 63;
        float mu = stats[c] * invN;
        float var = fmaf(-mu, mu, stats[DIM + c] * invN);
        float x = (h[i] - mu) * rsqrtf(var + 1e-5f) * g[c] + beta[c];
        if (do_elu && x < 0.f) x = expm1f(x);
        h[i] = x;
    }
}

// ---------------- launch ----------------

extern "C" void kernel_launch(void* const* d_in, const int* in_sizes, int n_in,
                              void* d_out, int out_size, void* d_ws, size_t ws_size,
                              hipStream_t stream) {
    const float* nw = (const float*)d_in[0];
    const int* src = (const int*)d_in[2];
    const int* dst = (const int*)d_in[3];
    const int N = in_sizes[0] / DIM;
    const int E = in_sizes[2];
    const float invN = 1.f / (float)N;

    char* ws = (char*)d_ws;
    size_t off = 0;
    auto alloc = [&](size_t bytes) -> void* {
        void* p = ws + off;
        off += (bytes + 255) & ~(size_t)255;
        return p;
    };
    int* counts     = (int*)alloc((size_t)N * 4);
    int* row_ptr    = (int*)alloc(((size_t)N + 1) * 4);
    int* blk_sums   = (int*)alloc(512);
    int* src_sorted = (int*)alloc((size_t)E * 4);
    float* ebuf     = (float*)alloc((size_t)E * 4);   // e scores, then alpha in place
    float* el       = (float*)alloc((size_t)N * 4);
    float* er       = (float*)alloc((size_t)N * 4);
    float* feat     = (float*)alloc((size_t)N * DIM * 4);
    float* hbuf     = (float*)alloc((size_t)N * DIM * 4);
    float* stats    = (float*)alloc(512);

    int egrid = (E + 255) / 256;
    int nb = (N + 1023) / 1024;  // <= 128

    // CSR build (once; same graph for all 3 layers)
    hipMemsetAsync(counts, 0, (size_t)N * 4, stream);
    count_kernel<<<egrid, 256, 0, stream>>>(dst, counts, E);
    scan1_kernel<<<nb, 256, 0, stream>>>(counts, row_ptr, blk_sums, N);
    scan2_kernel<<<1, 128, 0, stream>>>(blk_sums, nb);
    scan3_kernel<<<(N + 255) / 256, 256, 0, stream>>>(row_ptr, blk_sums, N, E);
    hipMemsetAsync(counts, 0, (size_t)N * 4, stream);  // reuse as fill
    scatter_kernel<<<egrid, 256, 0, stream>>>(src, dst, row_ptr, counts, src_sorted, E);

    for (int l = 0; l < 3; l++) {
        const float* W    = (const float*)d_in[4 + 6 * l];
        const float* al   = (const float*)d_in[5 + 6 * l];
        const float* ar   = (const float*)d_in[6 + 6 * l];
        const float* b    = (const float*)d_in[7 + 6 * l];
        const float* g    = (const float*)d_in[8 + 6 * l];
        const float* beta = (const float*)d_in[9 + 6 * l];
        const float* hin = (l == 0) ? nw : hbuf;
        float* hout = (l == 2) ? (float*)d_out : hbuf;

        // BN+ELU of previous layer fused into the GEMM input load
        gemm64_kernel<<<1024, 256, 0, stream>>>(hin, W, al, ar, stats,
                                                (l == 0) ? al : (const float*)d_in[8 + 6 * (l - 1)],
                                                (l == 0) ? al : (const float*)d_in[9 + 6 * (l - 1)],
                                                (l > 0) ? 1 : 0, invN,
                                                feat, el, er, N);
        attn_kernel<<<(N + 15) / 16, 256, 0, stream>>>(row_ptr, src_sorted, el, er, ebuf, N);
        aggregate_kernel<<<(N + 3) / 4, 256, 0, stream>>>(row_ptr, src_sorted, ebuf,
                                                          feat, b, hout, N);
        hipMemsetAsync(stats, 0, 512, stream);
        bn_stats_kernel<<<512, 256, 0, stream>>>(hout, stats, N);
    }
    // final BatchNorm (no ELU) on d_out
    bn_apply_kernel<<<2048, 256, 0, stream>>>((float*)d_out, stats,
                                              (const float*)d_in[8 + 12],
                                              (const float*)d_in[9 + 12],
                                              N, 0);
}

// Round 3
// 776.286 us; speedup vs baseline: 1.5533x; 1.1466x over previous
//
#include <hip/hip_runtime.h>
#include <hip/hip_bf16.h>
#include <math.h>

#define DIM 64
#define BSHIFT 9
#define BNODES 512   // 1 << BSHIFT
#define MAXB 256     // max coarse buckets (N <= 131072)
#define EPT 8
#define CHUNK 2048   // EPT * 256

// ---------------- CSR build: binned 2-pass sort ----------------

__global__ void bin_count_kernel(const int* __restrict__ dst, int* __restrict__ bucket_cnt, int E) {
    __shared__ int h[MAXB];
    int t = threadIdx.x;
    h[t] = 0;
    __syncthreads();
    for (int i = blockIdx.x * blockDim.x + t; i < E; i += gridDim.x * blockDim.x)
        atomicAdd(&h[dst[i] >> BSHIFT], 1);
    __syncthreads();
    if (h[t]) atomicAdd(&bucket_cnt[t], h[t]);
}

// single block, 256 threads: exclusive scan of bucket_cnt + zero fill counters
__global__ void bucket_scan_kernel(const int* __restrict__ bucket_cnt,
                                   int* __restrict__ bucket_off, int* __restrict__ bucket_fill) {
    __shared__ int s[MAXB];
    int t = threadIdx.x;
    int v = bucket_cnt[t];
    s[t] = v;
    __syncthreads();
    for (int off = 1; off < MAXB; off <<= 1) {
        int x = (t >= off) ? s[t - off] : 0;
        __syncthreads();
        s[t] += x;
        __syncthreads();
    }
    bucket_off[t] = s[t] - v;
    bucket_fill[t] = 0;
}

// block-local LDS binning + bulk reservation; writes (dst<<32|src) pairs in
// contiguous per-bucket runs (~20 edges = 160B per block per bucket)
__global__ __launch_bounds__(256) void bin_scatter_kernel(
    const int* __restrict__ src, const int* __restrict__ dst,
    const int* __restrict__ bucket_off, int* __restrict__ bucket_fill,
    unsigned long long* __restrict__ binned, int E) {
    __shared__ int lcnt[MAXB];
    __shared__ int lbase[MAXB];
    int t = threadIdx.x;
    lcnt[t] = 0;
    __syncthreads();
    int base = blockIdx.x * CHUNK;
    unsigned long long pair[EPT];
    int slot[EPT];
#pragma unroll
    for (int j = 0; j < EPT; j++) {
        int idx = base + j * 256 + t;
        if (idx < E) {
            int s = src[idx], d = dst[idx];
            pair[j] = ((unsigned long long)(unsigned)d << 32) | (unsigned)s;
            slot[j] = atomicAdd(&lcnt[d >> BSHIFT], 1);
        } else {
            slot[j] = -1;
        }
    }
    __syncthreads();
    int c = lcnt[t];
    if (c) lbase[t] = atomicAdd(&bucket_fill[t], c);
    __syncthreads();
#pragma unroll
    for (int j = 0; j < EPT; j++) {
        if (slot[j] >= 0) {
            int b = (int)(pair[j] >> 32) >> BSHIFT;
            binned[(size_t)bucket_off[b] + lbase[b] + slot[j]] = pair[j];
        }
    }
}

// per-node degree counts via LDS atomics (one block per bucket)
__global__ __launch_bounds__(256) void node_count_kernel(
    const unsigned long long* __restrict__ binned, const int* __restrict__ bucket_off,
    const int* __restrict__ bucket_cnt, int* __restrict__ counts, int N) {
    __shared__ int cnt[BNODES];
    int b = blockIdx.x, t = threadIdx.x;
    for (int i = t; i < BNODES; i += 256) cnt[i] = 0;
    __syncthreads();
    int s0 = bucket_off[b], c = bucket_cnt[b];
    for (int i = t; i < c; i += 256) {
        int d = (int)(binned[(size_t)s0 + i] >> 32);
        atomicAdd(&cnt[d & (BNODES - 1)], 1);
    }
    __syncthreads();
    int nbase = b << BSHIFT;
    for (int i = t; i < BNODES; i += 256)
        if (nbase + i < N) counts[nbase + i] = cnt[i];
}

// 256 threads, 4 elems/thread => 1024 elems/block
__global__ void scan1_kernel(const int* __restrict__ counts, int* __restrict__ excl,
                             int* __restrict__ blk_sums, int n) {
    __shared__ int sdata[256];
    int t = threadIdx.x;
    int base = blockIdx.x * 1024 + t * 4;
    int v0 = (base + 0 < n) ? counts[base + 0] : 0;
    int v1 = (base + 1 < n) ? counts[base + 1] : 0;
    int v2 = (base + 2 < n) ? counts[base + 2] : 0;
    int v3 = (base + 3 < n) ? counts[base + 3] : 0;
    int tsum = v0 + v1 + v2 + v3;
    sdata[t] = tsum;
    __syncthreads();
    for (int off = 1; off < 256; off <<= 1) {
        int x = (t >= off) ? sdata[t - off] : 0;
        __syncthreads();
        sdata[t] += x;
        __syncthreads();
    }
    int run = sdata[t] - tsum;
    if (base + 0 < n) excl[base + 0] = run; run += v0;
    if (base + 1 < n) excl[base + 1] = run; run += v1;
    if (base + 2 < n) excl[base + 2] = run; run += v2;
    if (base + 3 < n) excl[base + 3] = run;
    if (t == 255) blk_sums[blockIdx.x] = sdata[255];
}

// single block, nb <= 128
__global__ void scan2_kernel(int* __restrict__ blk_sums, int nb) {
    __shared__ int s[128];
    int t = threadIdx.x;
    s[t] = (t < nb) ? blk_sums[t] : 0;
    __syncthreads();
    for (int off = 1; off < 128; off <<= 1) {
        int x = (t >= off) ? s[t - off] : 0;
        __syncthreads();
        s[t] += x;
        __syncthreads();
    }
    if (t < nb) blk_sums[t] = (t > 0) ? s[t - 1] : 0;
}

__global__ void scan3_kernel(int* __restrict__ excl, const int* __restrict__ blk_sums,
                             int n, int total) {
    int i = blockIdx.x * blockDim.x + threadIdx.x;
    if (i < n) excl[i] += blk_sums[i >> 10];
    if (i == 0) excl[n] = total;
}

// final scatter: random writes confined to ~32KB CSR window per bucket (L2-coalesced)
__global__ __launch_bounds__(256) void final_scatter_kernel(
    const unsigned long long* __restrict__ binned, const int* __restrict__ bucket_off,
    const int* __restrict__ bucket_cnt, const int* __restrict__ row_ptr,
    int* __restrict__ src_sorted, int N) {
    __shared__ int fill[BNODES];
    int b = blockIdx.x, t = threadIdx.x;
    for (int i = t; i < BNODES; i += 256) fill[i] = 0;
    __syncthreads();
    int s0 = bucket_off[b], c = bucket_cnt[b];
    for (int i = t; i < c; i += 256) {
        unsigned long long p = binned[(size_t)s0 + i];
        int d = (int)(p >> 32);
        int pos = row_ptr[d] + atomicAdd(&fill[d & (BNODES - 1)], 1);
        src_sorted[pos] = (int)(p & 0xffffffffu);
    }
}

// ---------------- per-layer kernels ----------------

// feat(bf16) = bnelu(h) @ W ; el = feat.al ; er = feat.ar   (one wave per row)
__global__ __launch_bounds__(256) void gemm64_kernel(
    const float* __restrict__ h, const float* __restrict__ W,
    const float* __restrict__ al, const float* __restrict__ ar,
    const float* __restrict__ stats, const float* __restrict__ g,
    const float* __restrict__ beta, int do_bn, float invN,
    __hip_bfloat16* __restrict__ feat, float* __restrict__ el, float* __restrict__ er, int n) {
    __shared__ float Ws[DIM * DIM];
    __shared__ float avec[2 * DIM];
    int t = threadIdx.x;
    for (int i = t; i < DIM * DIM; i += 256) Ws[i] = W[i];
    if (t < 2 * DIM) avec[t] = (t < DIM) ? al[t] : ar[t - DIM];
    __syncthreads();
    int lane = t & 63;
    int w = t >> 6;
    float a_l = avec[lane], a_r = avec[DIM + lane];
    float scale = 1.f, shift = 0.f;
    if (do_bn) {
        float mu = stats[lane] * invN;
        float var = fmaf(-mu, mu, stats[DIM + lane] * invN);
        float inv = rsqrtf(var + 1e-5f) * g[lane];
        scale = inv;
        shift = beta[lane] - mu * inv;
    }
    int stride = gridDim.x * 4;
    for (int row = blockIdx.x * 4 + w; row < n; row += stride) {
        float hv = h[(size_t)row * DIM + lane];
        if (do_bn) {
            hv = fmaf(hv, scale, shift);
            if (hv < 0.f) hv = expm1f(hv);   // ELU
        }
        float acc = 0.f;
#pragma unroll
        for (int k = 0; k < DIM; k++) {
            acc = fmaf(__shfl(hv, k, 64), Ws[k * DIM + lane], acc);
        }
        feat[(size_t)row * DIM + lane] = __float2bfloat16(acc);
        float pl = acc * a_l, pr = acc * a_r;
#pragma unroll
        for (int off = 32; off; off >>= 1) {
            pl += __shfl_down(pl, off, 64);
            pr += __shfl_down(pr, off, 64);
        }
        if (lane == 0) { el[row] = pl; er[row] = pr; }
    }
}

// Fused: edge score (leaky-relu) + per-dst softmax + alpha (in place).
// One quarter-wave (16 lanes) per dst node.
__global__ __launch_bounds__(256) void attn_kernel(
    const int* __restrict__ row_ptr, const int* __restrict__ src_sorted,
    const float* __restrict__ el, const float* __restrict__ er,
    float* __restrict__ ebuf, int n) {
    int t = threadIdx.x;
    int li = t & 15;
    int node = blockIdx.x * 16 + (t >> 4);
    if (node >= n) return;
    int start = row_ptr[node], end = row_ptr[node + 1];
    float er_n = er[node];

    float m = -INFINITY, s = 0.f;
    for (int i = start + li; i < end; i += 16) {
        float v = el[src_sorted[i]] + er_n;
        v = (v > 0.f) ? v : 0.2f * v;
        ebuf[i] = v;
        float mn = fmaxf(m, v);
        s = s * __expf(m - mn) + __expf(v - mn);
        m = mn;
    }
#pragma unroll
    for (int off = 8; off; off >>= 1) {
        float mo = __shfl_xor(m, off, 64);
        float so = __shfl_xor(s, off, 64);
        float mn = fmaxf(m, mo);
        float sa = (m == -INFINITY) ? 0.f : s * __expf(m - mn);
        float sb = (mo == -INFINITY) ? 0.f : so * __expf(mo - mn);
        s = sa + sb;
        m = mn;
    }
    float inv_s = (s > 0.f) ? 1.f / s : 0.f;
    for (int i = start + li; i < end; i += 16) {
        ebuf[i] = __expf(ebuf[i] - m) * inv_s;
    }
}

// one wave per dst node; 4 quarter-waves = 4 edges in flight; lane holds
// 4 dims as bf16x4 (uint2 = 8B gather per lane, 128B per edge row).
__global__ __launch_bounds__(256) void aggregate_kernel(
    const int* __restrict__ row_ptr, const int* __restrict__ src_sorted,
    const float* __restrict__ alpha, const __hip_bfloat16* __restrict__ feat,
    const float* __restrict__ bias, float* __restrict__ out, int n) {
    int t = threadIdx.x, lane = t & 63;
    int q = lane >> 4;
    int li = lane & 15;
    int node = blockIdx.x * 4 + (t >> 6);
    if (node >= n) return;
    int start = row_ptr[node], end = row_ptr[node + 1];
    const uint2* featv = (const uint2*)feat;

    float4 acc = {0.f, 0.f, 0.f, 0.f};
    int i = start;
    for (; i + 4 <= end; i += 4) {
        int idx = i + q;
        float a = alpha[idx];
        int sn = src_sorted[idx];
        uint2 p = featv[(size_t)sn * 16 + li];
        acc.x = fmaf(a, __uint_as_float(p.x << 16), acc.x);
        acc.y = fmaf(a, __uint_as_float(p.x & 0xffff0000u), acc.y);
        acc.z = fmaf(a, __uint_as_float(p.y << 16), acc.z);
        acc.w = fmaf(a, __uint_as_float(p.y & 0xffff0000u), acc.w);
    }
    if (i < end) {
        int idx = i + q;
        bool valid = idx < end;
        int idc = valid ? idx : end - 1;
        float a = valid ? alpha[idc] : 0.f;
        int sn = src_sorted[idc];
        uint2 p = featv[(size_t)sn * 16 + li];
        acc.x = fmaf(a, __uint_as_float(p.x << 16), acc.x);
        acc.y = fmaf(a, __uint_as_float(p.x & 0xffff0000u), acc.y);
        acc.z = fmaf(a, __uint_as_float(p.y << 16), acc.z);
        acc.w = fmaf(a, __uint_as_float(p.y & 0xffff0000u), acc.w);
    }
#pragma unroll
    for (int off = 16; off <= 32; off <<= 1) {
        acc.x += __shfl_xor(acc.x, off, 64);
        acc.y += __shfl_xor(acc.y, off, 64);
        acc.z += __shfl_xor(acc.z, off, 64);
        acc.w += __shfl_xor(acc.w, off, 64);
    }
    if (q == 0) {
        float4 b4 = ((const float4*)bias)[li];
        acc.x += b4.x; acc.y += b4.y; acc.z += b4.z; acc.w += b4.w;
        ((float4*)out)[(size_t)node * 16 + li] = acc;
    }
}

// column sums / sumsq
__global__ __launch_bounds__(256) void bn_stats_kernel(const float* __restrict__ h,
                                                       float* __restrict__ stats, int n) {
    __shared__ float ls[256], lss[256];
    int t = threadIdx.x, lane = t & 63;
    int w = blockIdx.x * 4 + (t >> 6);
    int stride = gridDim.x * 4;
    float s = 0.f, ss = 0.f;
    for (int row = w; row < n; row += stride) {
        float v = h[(size_t)row * DIM + lane];
        s += v;
        ss = fmaf(v, v, ss);
    }
    ls[t] = s; lss[t] = ss;
    __syncthreads();
    if (t < 64) {
        float a = ls[t] + ls[t + 64] + ls[t + 128] + ls[t + 192];
        float b = lss[t] + lss[t + 64] + lss[t + 128] + lss[t + 192];
        atomicAdd(&stats[t], a);
        atomicAdd(&stats[64 + t], b);
    }
}

__global__ void bn_apply_kernel(float* __restrict__ h, const float* __restrict__ stats,
                                const float* __restrict__ g, const float* __restrict__ beta,
                                int n, int do_elu) {
    int i = blockIdx.x * blockDim.x + threadIdx.x;
    int total = n * DIM;
    int stride = gridDim.x * blockDim.x;
    float invN = 1.f / (float)n;
    for (; i < total; i += stride) {
        int c = i & 63;
        float mu = stats[c] * invN;
        float var = fmaf(-mu, mu, stats[DIM + c] * invN);
        float x = (h[i] - mu) * rsqrtf(var + 1e-5f) * g[c] + beta[c];
        if (do_elu && x < 0.f) x = expm1f(x);
        h[i] = x;
    }
}

// ---------------- launch ----------------

extern "C" void kernel_launch(void* const* d_in, const int* in_sizes, int n_in,
                              void* d_out, int out_size, void* d_ws, size_t ws_size,
                              hipStream_t stream) {
    const float* nw = (const float*)d_in[0];
    const int* src = (const int*)d_in[2];
    const int* dst = (const int*)d_in[3];
    const int N = in_sizes[0] / DIM;
    const int E = in_sizes[2];
    const float invN = 1.f / (float)N;
    const int nbuck = (N + BNODES - 1) >> BSHIFT;   // 196 for N=100k (<=256)

    char* ws = (char*)d_ws;
    size_t off = 0;
    auto alloc = [&](size_t bytes) -> void* {
        void* p = ws + off;
        off += (bytes + 255) & ~(size_t)255;
        return p;
    };
    int* counts       = (int*)alloc((size_t)N * 4);
    int* row_ptr      = (int*)alloc(((size_t)N + 1) * 4);
    int* blk_sums     = (int*)alloc(512);
    int* bucket_cnt   = (int*)alloc(MAXB * 4);
    int* bucket_off   = (int*)alloc(MAXB * 4);
    int* bucket_fill  = (int*)alloc(MAXB * 4);
    unsigned long long* binned = (unsigned long long*)alloc((size_t)E * 8);
    int* src_sorted   = (int*)alloc((size_t)E * 4);
    float* ebuf       = (float*)alloc((size_t)E * 4);
    float* el         = (float*)alloc((size_t)N * 4);
    float* er         = (float*)alloc((size_t)N * 4);
    __hip_bfloat16* feat = (__hip_bfloat16*)alloc((size_t)N * DIM * 2);
    float* hbuf       = (float*)alloc((size_t)N * DIM * 4);
    float* stats      = (float*)alloc(512);

    int nb = (N + 1023) / 1024;  // <= 128

    // CSR build (once; same graph for all 3 layers)
    hipMemsetAsync(bucket_cnt, 0, MAXB * 4, stream);
    bin_count_kernel<<<256, 256, 0, stream>>>(dst, bucket_cnt, E);
    bucket_scan_kernel<<<1, MAXB, 0, stream>>>(bucket_cnt, bucket_off, bucket_fill);
    bin_scatter_kernel<<<(E + CHUNK - 1) / CHUNK, 256, 0, stream>>>(
        src, dst, bucket_off, bucket_fill, binned, E);
    node_count_kernel<<<nbuck, 256, 0, stream>>>(binned, bucket_off, bucket_cnt, counts, N);
    scan1_kernel<<<nb, 256, 0, stream>>>(counts, row_ptr, blk_sums, N);
    scan2_kernel<<<1, 128, 0, stream>>>(blk_sums, nb);
    scan3_kernel<<<(N + 255) / 256, 256, 0, stream>>>(row_ptr, blk_sums, N, E);
    final_scatter_kernel<<<nbuck, 256, 0, stream>>>(binned, bucket_off, bucket_cnt,
                                                    row_ptr, src_sorted, N);

    for (int l = 0; l < 3; l++) {
        const float* W    = (const float*)d_in[4 + 6 * l];
        const float* al   = (const float*)d_in[5 + 6 * l];
        const float* ar   = (const float*)d_in[6 + 6 * l];
        const float* b    = (const float*)d_in[7 + 6 * l];
        const float* g    = (const float*)d_in[8 + 6 * l];
        const float* beta = (const float*)d_in[9 + 6 * l];
        const float* hin = (l == 0) ? nw : hbuf;
        float* hout = (l == 2) ? (float*)d_out : hbuf;

        gemm64_kernel<<<1024, 256, 0, stream>>>(hin, W, al, ar, stats,
                                                (l == 0) ? al : (const float*)d_in[8 + 6 * (l - 1)],
                                                (l == 0) ? al : (const float*)d_in[9 + 6 * (l - 1)],
                                                (l > 0) ? 1 : 0, invN,
                                                feat, el, er, N);
        attn_kernel<<<(N + 15) / 16, 256, 0, stream>>>(row_ptr, src_sorted, el, er, ebuf, N);
        aggregate_kernel<<<(N + 3) / 4, 256, 0, stream>>>(row_ptr, src_sorted, ebuf,
                                                          feat, b, hout, N);
        hipMemsetAsync(stats, 0, 512, stream);
        bn_stats_kernel<<<512, 256, 0, stream>>>(hout, stats, N);
    }
    // final BatchNorm (no ELU) on d_out
    bn_apply_kernel<<<2048, 256, 0, stream>>>((float*)d_out, stats,
                                              (const float*)d_in[8 + 12],
                                              (const float*)d_in[9 + 12],
                                              N, 0);
}

// Round 4
// 517.216 us; speedup vs baseline: 2.3314x; 1.5009x over previous
//
#include <hip/hip_runtime.h>
#include <hip/hip_bf16.h>
#include <math.h>

#define DIM 64
#define BSHIFT 9
#define BNODES 512   // 1 << BSHIFT
#define MAXB 256     // max coarse buckets (N <= 131072)
#define EPT 8
#define CHUNK 2048   // EPT * 256

typedef __attribute__((ext_vector_type(8))) short bf16x8;
typedef __attribute__((ext_vector_type(4))) float f32x4;

__device__ __forceinline__ short f2bf(float x) {
    union { __hip_bfloat16 b; short s; } u;
    u.b = __float2bfloat16(x);
    return u.s;
}
__device__ __forceinline__ float bf2f(short s) {
    return __uint_as_float(((unsigned)(unsigned short)s) << 16);
}

// ---------------- CSR build: binned 2-pass sort ----------------

__global__ void bin_count_kernel(const int* __restrict__ dst, int* __restrict__ bucket_cnt, int E) {
    __shared__ int h[MAXB];
    int t = threadIdx.x;
    h[t] = 0;
    __syncthreads();
    for (int i = blockIdx.x * blockDim.x + t; i < E; i += gridDim.x * blockDim.x)
        atomicAdd(&h[dst[i] >> BSHIFT], 1);
    __syncthreads();
    if (h[t]) atomicAdd(&bucket_cnt[t], h[t]);
}

__global__ void bucket_scan_kernel(const int* __restrict__ bucket_cnt,
                                   int* __restrict__ bucket_off, int* __restrict__ bucket_fill) {
    __shared__ int s[MAXB];
    int t = threadIdx.x;
    int v = bucket_cnt[t];
    s[t] = v;
    __syncthreads();
    for (int off = 1; off < MAXB; off <<= 1) {
        int x = (t >= off) ? s[t - off] : 0;
        __syncthreads();
        s[t] += x;
        __syncthreads();
    }
    bucket_off[t] = s[t] - v;
    bucket_fill[t] = 0;
}

__global__ __launch_bounds__(256) void bin_scatter_kernel(
    const int* __restrict__ src, const int* __restrict__ dst,
    const int* __restrict__ bucket_off, int* __restrict__ bucket_fill,
    unsigned long long* __restrict__ binned, int E) {
    __shared__ int lcnt[MAXB];
    __shared__ int lbase[MAXB];
    int t = threadIdx.x;
    lcnt[t] = 0;
    __syncthreads();
    int base = blockIdx.x * CHUNK;
    unsigned long long pair[EPT];
    int slot[EPT];
#pragma unroll
    for (int j = 0; j < EPT; j++) {
        int idx = base + j * 256 + t;
        if (idx < E) {
            int s = src[idx], d = dst[idx];
            pair[j] = ((unsigned long long)(unsigned)d << 32) | (unsigned)s;
            slot[j] = atomicAdd(&lcnt[d >> BSHIFT], 1);
        } else {
            slot[j] = -1;
        }
    }
    __syncthreads();
    int c = lcnt[t];
    if (c) lbase[t] = atomicAdd(&bucket_fill[t], c);
    __syncthreads();
#pragma unroll
    for (int j = 0; j < EPT; j++) {
        if (slot[j] >= 0) {
            int b = (int)(pair[j] >> 32) >> BSHIFT;
            binned[(size_t)bucket_off[b] + lbase[b] + slot[j]] = pair[j];
        }
    }
}

__global__ __launch_bounds__(256) void node_count_kernel(
    const unsigned long long* __restrict__ binned, const int* __restrict__ bucket_off,
    const int* __restrict__ bucket_cnt, int* __restrict__ counts, int N) {
    __shared__ int cnt[BNODES];
    int b = blockIdx.x, t = threadIdx.x;
    for (int i = t; i < BNODES; i += 256) cnt[i] = 0;
    __syncthreads();
    int s0 = bucket_off[b], c = bucket_cnt[b];
    for (int i = t; i < c; i += 256) {
        int d = (int)(binned[(size_t)s0 + i] >> 32);
        atomicAdd(&cnt[d & (BNODES - 1)], 1);
    }
    __syncthreads();
    int nbase = b << BSHIFT;
    for (int i = t; i < BNODES; i += 256)
        if (nbase + i < N) counts[nbase + i] = cnt[i];
}

__global__ void scan1_kernel(const int* __restrict__ counts, int* __restrict__ excl,
                             int* __restrict__ blk_sums, int n) {
    __shared__ int sdata[256];
    int t = threadIdx.x;
    int base = blockIdx.x * 1024 + t * 4;
    int v0 = (base + 0 < n) ? counts[base + 0] : 0;
    int v1 = (base + 1 < n) ? counts[base + 1] : 0;
    int v2 = (base + 2 < n) ? counts[base + 2] : 0;
    int v3 = (base + 3 < n) ? counts[base + 3] : 0;
    int tsum = v0 + v1 + v2 + v3;
    sdata[t] = tsum;
    __syncthreads();
    for (int off = 1; off < 256; off <<= 1) {
        int x = (t >= off) ? sdata[t - off] : 0;
        __syncthreads();
        sdata[t] += x;
        __syncthreads();
    }
    int run = sdata[t] - tsum;
    if (base + 0 < n) excl[base + 0] = run; run += v0;
    if (base + 1 < n) excl[base + 1] = run; run += v1;
    if (base + 2 < n) excl[base + 2] = run; run += v2;
    if (base + 3 < n) excl[base + 3] = run;
    if (t == 255) blk_sums[blockIdx.x] = sdata[255];
}

__global__ void scan2_kernel(int* __restrict__ blk_sums, int nb) {
    __shared__ int s[128];
    int t = threadIdx.x;
    s[t] = (t < nb) ? blk_sums[t] : 0;
    __syncthreads();
    for (int off = 1; off < 128; off <<= 1) {
        int x = (t >= off) ? s[t - off] : 0;
        __syncthreads();
        s[t] += x;
        __syncthreads();
    }
    if (t < nb) blk_sums[t] = (t > 0) ? s[t - 1] : 0;
}

__global__ void scan3_kernel(int* __restrict__ excl, const int* __restrict__ blk_sums,
                             int n, int total) {
    int i = blockIdx.x * blockDim.x + threadIdx.x;
    if (i < n) excl[i] += blk_sums[i >> 10];
    if (i == 0) excl[n] = total;
}

__global__ __launch_bounds__(256) void final_scatter_kernel(
    const unsigned long long* __restrict__ binned, const int* __restrict__ bucket_off,
    const int* __restrict__ bucket_cnt, const int* __restrict__ row_ptr,
    int* __restrict__ src_sorted, int N) {
    __shared__ int fill[BNODES];
    int b = blockIdx.x, t = threadIdx.x;
    for (int i = t; i < BNODES; i += 256) fill[i] = 0;
    __syncthreads();
    int s0 = bucket_off[b], c = bucket_cnt[b];
    for (int i = t; i < c; i += 256) {
        unsigned long long p = binned[(size_t)s0 + i];
        int d = (int)(p >> 32);
        int pos = row_ptr[d] + atomicAdd(&fill[d & (BNODES - 1)], 1);
        src_sorted[pos] = (int)(p & 0xffffffffu);
    }
}

// ---------------- per-layer kernels ----------------

// MFMA GEMM: feat(bf16) = bnelu(h) @ W ; el = feat.al ; er = feat.ar
// One wave per 16-row tile. W held in registers as hi/lo bf16 split-precision
// fragments; 3 MFMA passes give ~f32 accuracy. No LDS, no shuffles in the
// main loop (kills the ds_bpermute storm of the old kernel).
// A-frag: A[m=lane&15][k=(lane>>4)*8+j]; B-frag: B[k=(lane>>4)*8+j][n=lane&15];
// C/D: row=(lane>>4)*4+reg, col=lane&15   [learn_hip m89-verified layouts]
__global__ __launch_bounds__(256) void gemm64_mfma_kernel(
    const float* __restrict__ h, const float* __restrict__ W,
    const float* __restrict__ al, const float* __restrict__ ar,
    const float* __restrict__ stats, const float* __restrict__ g,
    const float* __restrict__ beta, int do_bn, float invN,
    __hip_bfloat16* __restrict__ feat, float* __restrict__ el, float* __restrict__ er,
    int n) {
    int t = threadIdx.x;
    int lane = t & 63;
    int li = lane & 15;
    int quad = lane >> 4;
    int wv = t >> 6;

    // B fragments (W is row-major W[k][n])
    bf16x8 b_hi[2][4], b_lo[2][4];
#pragma unroll
    for (int ks = 0; ks < 2; ks++)
#pragma unroll
        for (int nt = 0; nt < 4; nt++) {
#pragma unroll
            for (int j = 0; j < 8; j++) {
                float w = W[(ks * 32 + quad * 8 + j) * 64 + nt * 16 + li];
                short hi = f2bf(w);
                b_hi[ks][nt][j] = hi;
                b_lo[ks][nt][j] = f2bf(w - bf2f(hi));
            }
        }
    float alv[4], arv[4];
#pragma unroll
    for (int nt = 0; nt < 4; nt++) { alv[nt] = al[nt * 16 + li]; arv[nt] = ar[nt * 16 + li]; }

    // BN scale/shift for input channels this lane touches: k = ks*32 + quad*8 + j
    float sc[2][8], sh[2][8];
    if (do_bn) {
#pragma unroll
        for (int ks = 0; ks < 2; ks++)
#pragma unroll
            for (int j = 0; j < 8; j++) {
                int k = ks * 32 + quad * 8 + j;
                float mu = stats[k] * invN;
                float var = fmaf(-mu, mu, stats[64 + k] * invN);
                float inv = rsqrtf(var + 1e-5f) * g[k];
                sc[ks][j] = inv;
                sh[ks][j] = beta[k] - mu * inv;
            }
    }

    int ntiles = (n + 15) >> 4;
    for (int tile = blockIdx.x * 4 + wv; tile < ntiles; tile += gridDim.x * 4) {
        int m0 = tile << 4;
        int rrow = m0 + li;
        const float* rowp = h + (size_t)((rrow < n) ? rrow : (n - 1)) * 64;
        bf16x8 a_hi[2], a_lo[2];
#pragma unroll
        for (int ks = 0; ks < 2; ks++) {
            float4 v0 = *(const float4*)(rowp + ks * 32 + quad * 8);
            float4 v1 = *(const float4*)(rowp + ks * 32 + quad * 8 + 4);
            float x[8] = {v0.x, v0.y, v0.z, v0.w, v1.x, v1.y, v1.z, v1.w};
#pragma unroll
            for (int j = 0; j < 8; j++) {
                float v = x[j];
                if (do_bn) {
                    v = fmaf(v, sc[ks][j], sh[ks][j]);
                    if (v < 0.f) v = expm1f(v);   // ELU
                }
                short hi = f2bf(v);
                a_hi[ks][j] = hi;
                a_lo[ks][j] = f2bf(v - bf2f(hi));
            }
        }
        f32x4 acc[4];
#pragma unroll
        for (int nt = 0; nt < 4; nt++) acc[nt] = (f32x4){0.f, 0.f, 0.f, 0.f};
#pragma unroll
        for (int ks = 0; ks < 2; ks++)
#pragma unroll
            for (int nt = 0; nt < 4; nt++) {
                acc[nt] = __builtin_amdgcn_mfma_f32_16x16x32_bf16(a_hi[ks], b_hi[ks][nt], acc[nt], 0, 0, 0);
                acc[nt] = __builtin_amdgcn_mfma_f32_16x16x32_bf16(a_lo[ks], b_hi[ks][nt], acc[nt], 0, 0, 0);
                acc[nt] = __builtin_amdgcn_mfma_f32_16x16x32_bf16(a_hi[ks], b_lo[ks][nt], acc[nt], 0, 0, 0);
            }
        // feat store (bf16)
#pragma unroll
        for (int nt = 0; nt < 4; nt++)
#pragma unroll
            for (int reg = 0; reg < 4; reg++) {
                int wrow = m0 + quad * 4 + reg;
                if (wrow < n) {
                    union { __hip_bfloat16 b; short s; } u;
                    u.s = f2bf(acc[nt][reg]);
                    feat[(size_t)wrow * 64 + nt * 16 + li] = u.b;
                }
            }
        // el/er epilogue: reduce over the 16 cols this quad's lanes hold
        float pl[4], pr[4];
#pragma unroll
        for (int reg = 0; reg < 4; reg++) {
            float l = 0.f, r = 0.f;
#pragma unroll
            for (int nt = 0; nt < 4; nt++) {
                l = fmaf(acc[nt][reg], alv[nt], l);
                r = fmaf(acc[nt][reg], arv[nt], r);
            }
#pragma unroll
            for (int off = 1; off < 16; off <<= 1) {
                l += __shfl_xor(l, off, 64);
                r += __shfl_xor(r, off, 64);
            }
            pl[reg] = l; pr[reg] = r;
        }
        int row = m0 + quad * 4;
        if (li == 0 && row < n)          { el[row] = pl[0]; er[row] = pr[0]; }
        else if (li == 1 && row + 1 < n) { el[row + 1] = pl[1]; er[row + 1] = pr[1]; }
        else if (li == 2 && row + 2 < n) { el[row + 2] = pl[2]; er[row + 2] = pr[2]; }
        else if (li == 3 && row + 3 < n) { el[row + 3] = pl[3]; er[row + 3] = pr[3]; }
    }
}

// Fused: edge score (leaky-relu) + per-dst softmax + alpha (in place).
// One quarter-wave (16 lanes) per dst node.
__global__ __launch_bounds__(256) void attn_kernel(
    const int* __restrict__ row_ptr, const int* __restrict__ src_sorted,
    const float* __restrict__ el, const float* __restrict__ er,
    float* __restrict__ ebuf, int n) {
    int t = threadIdx.x;
    int li = t & 15;
    int node = blockIdx.x * 16 + (t >> 4);
    if (node >= n) return;
    int start = row_ptr[node], end = row_ptr[node + 1];
    float er_n = er[node];

    float m = -INFINITY, s = 0.f;
    for (int i = start + li; i < end; i += 16) {
        float v = el[src_sorted[i]] + er_n;
        v = (v > 0.f) ? v : 0.2f * v;
        ebuf[i] = v;
        float mn = fmaxf(m, v);
        s = s * __expf(m - mn) + __expf(v - mn);
        m = mn;
    }
#pragma unroll
    for (int off = 8; off; off >>= 1) {
        float mo = __shfl_xor(m, off, 64);
        float so = __shfl_xor(s, off, 64);
        float mn = fmaxf(m, mo);
        float sa = (m == -INFINITY) ? 0.f : s * __expf(m - mn);
        float sb = (mo == -INFINITY) ? 0.f : so * __expf(mo - mn);
        s = sa + sb;
        m = mn;
    }
    float inv_s = (s > 0.f) ? 1.f / s : 0.f;
    for (int i = start + li; i < end; i += 16) {
        ebuf[i] = __expf(ebuf[i] - m) * inv_s;
    }
}

// one wave per dst node; 8 edge-slots of 8 lanes; lane holds 8 dims via one
// uint4 (16B) bf16 gather -> 8 edges in flight per wave.
__global__ __launch_bounds__(256) void aggregate_kernel(
    const int* __restrict__ row_ptr, const int* __restrict__ src_sorted,
    const float* __restrict__ alpha, const __hip_bfloat16* __restrict__ feat,
    const float* __restrict__ bias, float* __restrict__ out, int n) {
    int t = threadIdx.x, lane = t & 63;
    int q = lane >> 3;        // edge slot 0..7
    int li = lane & 7;        // dim octet 0..7
    int node = blockIdx.x * 4 + (t >> 6);
    if (node >= n) return;
    int start = row_ptr[node], end = row_ptr[node + 1];
    const uint4* featv = (const uint4*)feat;

    float a0 = 0.f, a1 = 0.f, a2 = 0.f, a3 = 0.f, a4 = 0.f, a5 = 0.f, a6 = 0.f, a7 = 0.f;
    int i = start;
    for (; i + 8 <= end; i += 8) {
        int idx = i + q;
        float a = alpha[idx];
        int sn = src_sorted[idx];
        uint4 p = featv[(size_t)sn * 8 + li];
        a0 = fmaf(a, __uint_as_float(p.x << 16), a0);
        a1 = fmaf(a, __uint_as_float(p.x & 0xffff0000u), a1);
        a2 = fmaf(a, __uint_as_float(p.y << 16), a2);
        a3 = fmaf(a, __uint_as_float(p.y & 0xffff0000u), a3);
        a4 = fmaf(a, __uint_as_float(p.z << 16), a4);
        a5 = fmaf(a, __uint_as_float(p.z & 0xffff0000u), a5);
        a6 = fmaf(a, __uint_as_float(p.w << 16), a6);
        a7 = fmaf(a, __uint_as_float(p.w & 0xffff0000u), a7);
    }
    if (i < end) {
        int idx = i + q;
        bool valid = idx < end;
        int idc = valid ? idx : end - 1;
        float a = valid ? alpha[idc] : 0.f;
        int sn = src_sorted[idc];
        uint4 p = featv[(size_t)sn * 8 + li];
        a0 = fmaf(a, __uint_as_float(p.x << 16), a0);
        a1 = fmaf(a, __uint_as_float(p.x & 0xffff0000u), a1);
        a2 = fmaf(a, __uint_as_float(p.y << 16), a2);
        a3 = fmaf(a, __uint_as_float(p.y & 0xffff0000u), a3);
        a4 = fmaf(a, __uint_as_float(p.z << 16), a4);
        a5 = fmaf(a, __uint_as_float(p.z & 0xffff0000u), a5);
        a6 = fmaf(a, __uint_as_float(p.w << 16), a6);
        a7 = fmaf(a, __uint_as_float(p.w & 0xffff0000u), a7);
    }
#pragma unroll
    for (int off = 8; off <= 32; off <<= 1) {
        a0 += __shfl_xor(a0, off, 64);
        a1 += __shfl_xor(a1, off, 64);
        a2 += __shfl_xor(a2, off, 64);
        a3 += __shfl_xor(a3, off, 64);
        a4 += __shfl_xor(a4, off, 64);
        a5 += __shfl_xor(a5, off, 64);
        a6 += __shfl_xor(a6, off, 64);
        a7 += __shfl_xor(a7, off, 64);
    }
    if (q == 0) {
        const float4* bv = (const float4*)bias;
        float4 b0 = bv[li * 2], b1 = bv[li * 2 + 1];
        float4 o0 = {a0 + b0.x, a1 + b0.y, a2 + b0.z, a3 + b0.w};
        float4 o1 = {a4 + b1.x, a5 + b1.y, a6 + b1.z, a7 + b1.w};
        float4* op = (float4*)(out + (size_t)node * 64 + li * 8);
        op[0] = o0;
        op[1] = o1;
    }
}

// column sums / sumsq
__global__ __launch_bounds__(256) void bn_stats_kernel(const float* __restrict__ h,
                                                       float* __restrict__ stats, int n) {
    __shared__ float ls[256], lss[256];
    int t = threadIdx.x, lane = t & 63;
    int w = blockIdx.x * 4 + (t >> 6);
    int stride = gridDim.x * 4;
    float s = 0.f, ss = 0.f;
    for (int row = w; row < n; row += stride) {
        float v = h[(size_t)row * DIM + lane];
        s += v;
        ss = fmaf(v, v, ss);
    }
    ls[t] = s; lss[t] = ss;
    __syncthreads();
    if (t < 64) {
        float a = ls[t] + ls[t + 64] + ls[t + 128] + ls[t + 192];
        float b = lss[t] + lss[t + 64] + lss[t + 128] + lss[t + 192];
        atomicAdd(&stats[t], a);
        atomicAdd(&stats[64 + t], b);
    }
}

__global__ void bn_apply_kernel(float* __restrict__ h, const float* __restrict__ stats,
                                const float* __restrict__ g, const float* __restrict__ beta,
                                int n, int do_elu) {
    int i = blockIdx.x * blockDim.x + threadIdx.x;
    int total = n * DIM;
    int stride = gridDim.x * blockDim.x;
    float invN = 1.f / (float)n;
    for (; i < total; i += stride) {
        int c = i & 63;
        float mu = stats[c] * invN;
        float var = fmaf(-mu, mu, stats[DIM + c] * invN);
        float x = (h[i] - mu) * rsqrtf(var + 1e-5f) * g[c] + beta[c];
        if (do_elu && x < 0.f) x = expm1f(x);
        h[i] = x;
    }
}

// ---------------- launch ----------------

extern "C" void kernel_launch(void* const* d_in, const int* in_sizes, int n_in,
                              void* d_out, int out_size, void* d_ws, size_t ws_size,
                              hipStream_t stream) {
    const float* nw = (const float*)d_in[0];
    const int* src = (const int*)d_in[2];
    const int* dst = (const int*)d_in[3];
    const int N = in_sizes[0] / DIM;
    const int E = in_sizes[2];
    const float invN = 1.f / (float)N;
    const int nbuck = (N + BNODES - 1) >> BSHIFT;

    char* ws = (char*)d_ws;
    size_t off = 0;
    auto alloc = [&](size_t bytes) -> void* {
        void* p = ws + off;
        off += (bytes + 255) & ~(size_t)255;
        return p;
    };
    int* counts       = (int*)alloc((size_t)N * 4);
    int* row_ptr      = (int*)alloc(((size_t)N + 1) * 4);
    int* blk_sums     = (int*)alloc(512);
    int* bucket_cnt   = (int*)alloc(MAXB * 4);
    int* bucket_off   = (int*)alloc(MAXB * 4);
    int* bucket_fill  = (int*)alloc(MAXB * 4);
    unsigned long long* binned = (unsigned long long*)alloc((size_t)E * 8);
    int* src_sorted   = (int*)alloc((size_t)E * 4);
    float* ebuf       = (float*)alloc((size_t)E * 4);
    float* el         = (float*)alloc((size_t)N * 4);
    float* er         = (float*)alloc((size_t)N * 4);
    __hip_bfloat16* feat = (__hip_bfloat16*)alloc((size_t)N * DIM * 2);
    float* hbuf       = (float*)alloc((size_t)N * DIM * 4);
    float* stats      = (float*)alloc(512);

    int nb = (N + 1023) / 1024;

    // CSR build (once; same graph for all 3 layers)
    hipMemsetAsync(bucket_cnt, 0, MAXB * 4, stream);
    bin_count_kernel<<<256, 256, 0, stream>>>(dst, bucket_cnt, E);
    bucket_scan_kernel<<<1, MAXB, 0, stream>>>(bucket_cnt, bucket_off, bucket_fill);
    bin_scatter_kernel<<<(E + CHUNK - 1) / CHUNK, 256, 0, stream>>>(
        src, dst, bucket_off, bucket_fill, binned, E);
    node_count_kernel<<<nbuck, 256, 0, stream>>>(binned, bucket_off, bucket_cnt, counts, N);
    scan1_kernel<<<nb, 256, 0, stream>>>(counts, row_ptr, blk_sums, N);
    scan2_kernel<<<1, 128, 0, stream>>>(blk_sums, nb);
    scan3_kernel<<<(N + 255) / 256, 256, 0, stream>>>(row_ptr, blk_sums, N, E);
    final_scatter_kernel<<<nbuck, 256, 0, stream>>>(binned, bucket_off, bucket_cnt,
                                                    row_ptr, src_sorted, N);

    for (int l = 0; l < 3; l++) {
        const float* W    = (const float*)d_in[4 + 6 * l];
        const float* al   = (const float*)d_in[5 + 6 * l];
        const float* ar   = (const float*)d_in[6 + 6 * l];
        const float* b    = (const float*)d_in[7 + 6 * l];
        const float* g    = (const float*)d_in[8 + 6 * l];
        const float* beta = (const float*)d_in[9 + 6 * l];
        const float* hin = (l == 0) ? nw : hbuf;
        float* hout = (l == 2) ? (float*)d_out : hbuf;

        gemm64_mfma_kernel<<<1024, 256, 0, stream>>>(
            hin, W, al, ar, stats,
            (l == 0) ? al : (const float*)d_in[8 + 6 * (l - 1)],
            (l == 0) ? al : (const float*)d_in[9 + 6 * (l - 1)],
            (l > 0) ? 1 : 0, invN,
            feat, el, er, N);
        attn_kernel<<<(N + 15) / 16, 256, 0, stream>>>(row_ptr, src_sorted, el, er, ebuf, N);
        aggregate_kernel<<<(N + 3) / 4, 256, 0, stream>>>(row_ptr, src_sorted, ebuf,
                                                          feat, b, hout, N);
        hipMemsetAsync(stats, 0, 512, stream);
        bn_stats_kernel<<<512, 256, 0, stream>>>(hout, stats, N);
    }
    // final BatchNorm (no ELU) on d_out
    bn_apply_kernel<<<2048, 256, 0, stream>>>((float*)d_out, stats,
                                              (const float*)d_in[8 + 12],
                                              (const float*)d_in[9 + 12],
                                              N, 0);
}